// Round 5
// baseline (1933.621 us; speedup 1.0000x reference)
//
#include <hip/hip_runtime.h>
#include <hip/hip_bf16.h>

// Problem constants: B=4,S=2048,H=2048,G=4,E=8,D=512,TOP_K=2
#define T_TOK   8192
#define HDIM    2048
#define DDIM    512
#define NGROUP  4
#define NEXP    8
#define NGE     32
#define CAP     4096   // mean count 2048, std 39 (binomial) -> 4096 is 52 sigma

typedef __attribute__((ext_vector_type(8))) short short8;
typedef __attribute__((ext_vector_type(4))) float f32x4;

struct alignas(16) U8 { ushort u[8]; };
struct alignas(8)  U4 { ushort u[4]; };

__device__ __forceinline__ ushort f2bf(float f) {
  union { __hip_bfloat16 h; ushort u; } c;
  c.h = __float2bfloat16(f);
  return c.u;
}

__device__ __forceinline__ void gload16(const void* g, void* l) {
  __builtin_amdgcn_global_load_lds(
      (const __attribute__((address_space(1))) void*)g,
      (__attribute__((address_space(3))) void*)l, 16, 0, 0);
}

// ---------------------------------------------------------------------------
// Gating v2: 8 tokens/block (gate_w L2 traffic 2GB -> 256MB). Wave g handles
// group g for all 8 tokens; a 9th pass computes x·orig_w[g] (fused final-path).
// Per-token arithmetic order identical to the round-4 passing kernel ->
// bit-identical routing. Fuses x -> bf16 conversion on the staging pass.
// ---------------------------------------------------------------------------
__global__ __launch_bounds__(256) void gating_kernel(
    const float* __restrict__ x, const float* __restrict__ gate_w,
    const float* __restrict__ orig_w,
    int* __restrict__ counts, int* __restrict__ ltok, float* __restrict__ lw,
    ushort* __restrict__ xbf, float* __restrict__ xorig) {
  const int t0 = blockIdx.x * 8;
  __shared__ float xsm[8 * HDIM];   // 64 KiB
  const int tid = threadIdx.x;

  // stage 8 token rows (coalesced) + fused bf16 conversion
  {
    const int r = tid >> 5;            // token slot 0..7
    const int ci = tid & 31;           // f4 column base
    const float4* xrow = (const float4*)(x + (size_t)(t0 + r) * HDIM);
    float4* xsrow = (float4*)(xsm + r * HDIM);
    ushort* xbrow = xbf + (size_t)(t0 + r) * HDIM;
#pragma unroll
    for (int q = 0; q < 16; q++) {
      int idx = ci + 32 * q;
      float4 v = xrow[idx];
      xsrow[idx] = v;
      U4 p; p.u[0] = f2bf(v.x); p.u[1] = f2bf(v.y);
      p.u[2] = f2bf(v.z); p.u[3] = f2bf(v.w);
      *(U4*)(xbrow + idx * 4) = p;
    }
  }
  __syncthreads();

  const int g = tid >> 6;      // wave = group
  const int lane = tid & 63;
  const float4* xs4 = (const float4*)xsm;

  float logits[NEXP];
  float ov = 0.f;              // x · orig_w[g]
#pragma unroll
  for (int e = 0; e < 9; e++) {
    const float* wrow = (e < 8) ? (gate_w + ((size_t)g * NEXP + e) * HDIM)
                                : (orig_w + (size_t)g * HDIM);
    const float4* gv = (const float4*)wrow;
    float s[8];
#pragma unroll
    for (int k = 0; k < 8; k++) s[k] = 0.f;
#pragma unroll
    for (int i = lane; i < HDIM / 4; i += 64) {
      float4 b = gv[i];
#pragma unroll
      for (int k = 0; k < 8; k++) {
        float4 a = xs4[k * (HDIM / 4) + i];
        s[k] += a.x * b.x + a.y * b.y + a.z * b.z + a.w * b.w;
      }
    }
#pragma unroll
    for (int k = 0; k < 8; k++)
#pragma unroll
      for (int off = 32; off; off >>= 1) s[k] += __shfl_xor(s[k], off);
    // lane j (<8) keeps token j's value (static-index select chain)
    float lg = s[0];
#pragma unroll
    for (int k = 1; k < 8; k++) lg = (lane == k) ? s[k] : lg;
    if (e < 8) logits[e] = lg; else ov = lg;
  }

  if (lane < 8) {
    const int t = t0 + lane;
    xorig[t * NGROUP + g] = ov;
    int i0 = 0; float l0 = logits[0];
#pragma unroll
    for (int e = 1; e < NEXP; e++)
      if (logits[e] > l0) { l0 = logits[e]; i0 = e; }
    int i1 = -1; float l1 = -1e30f;
#pragma unroll
    for (int e = 0; e < NEXP; e++) {
      if (e == i0) continue;
      if (logits[e] > l1) { l1 = logits[e]; i1 = e; }
    }
    float w0 = 1.f / (1.f + expf(l1 - l0));   // softmax->top2->renorm, exact
    float w1 = 1.f - w0;
    int ge0 = (g << 3) + i0;
    int ge1 = (g << 3) + i1;
    int p0 = atomicAdd(&counts[ge0], 1);
    if (p0 < CAP) { ltok[ge0 * CAP + p0] = t; lw[ge0 * CAP + p0] = w0; }
    int p1 = atomicAdd(&counts[ge1], 1);
    if (p1 < CAP) { ltok[ge1 * CAP + p1] = t; lw[ge1 * CAP + p1] = w1; }
  }
}

// ---------------------------------------------------------------------------
// expert_w fp32 -> bf16
// ---------------------------------------------------------------------------
__global__ __launch_bounds__(256) void convert_w(
    const float* __restrict__ w, ushort* __restrict__ wbf) {
  const int i = (blockIdx.x * 256 + threadIdx.x) * 8;
  float4 f0 = *(const float4*)(w + i);
  float4 f1 = *(const float4*)(w + i + 4);
  U8 pack;
  pack.u[0] = f2bf(f0.x); pack.u[1] = f2bf(f0.y);
  pack.u[2] = f2bf(f0.z); pack.u[3] = f2bf(f0.w);
  pack.u[4] = f2bf(f1.x); pack.u[5] = f2bf(f1.y);
  pack.u[6] = f2bf(f1.z); pack.u[7] = f2bf(f1.w);
  *(U8*)(wbf + i) = pack;
}

// ---------------------------------------------------------------------------
// Gathered bf16 MFMA expert GEMM v2: 256 tok x 256 d tile, BK=64, 512 thr
// (8 waves as 2Mx4N, 128x64 per wave). 128 FLOP/staged-byte (2x round 4).
// Bijective XCD swizzle: ge -> one XCD, so the expert's B panel is L2-resident.
// Staging/read swizzle identical to the verified round-4 scheme.
// ---------------------------------------------------------------------------
__global__ __launch_bounds__(512, 4) void expert_gemm_bf16(
    const ushort* __restrict__ xbf, const ushort* __restrict__ wbf,
    const float* __restrict__ expert_b, const int* __restrict__ counts,
    const int* __restrict__ ltok, const float* __restrict__ lw,
    float* __restrict__ avg_out) {
  // flat grid 1024 = 32 ge x 16 token-tiles x 2 d-tiles; XCD-chunked swizzle
  const int fid = blockIdx.x;
  const int swz = (fid & 7) * 128 + (fid >> 3);
  const int ge = swz >> 5;
  const int inner = swz & 31;
  const int dt = inner & 1, tt = inner >> 1;
  const int cnt = counts[ge];
  const int t0 = tt * 256;
  if (t0 >= cnt) return;
  const int d0 = dt * 256;

  __shared__ ushort As[256 * 64];   // 32 KiB
  __shared__ ushort Bs[256 * 64];   // 32 KiB
  __shared__ int   stok[256];
  __shared__ float srw[256];

  const int tid = threadIdx.x;
  const int w = tid >> 6, l = tid & 63;
  if (tid < 256) {
    int idx = t0 + tid;
    stok[tid] = (idx < cnt) ? ltok[ge * CAP + idx] : -1;
    srw[tid]  = (idx < cnt) ? lw[ge * CAP + idx] : 0.f;
  }
  __syncthreads();

  // staging: chunk c = i*8+w covers rows 8c..8c+7; linear LDS, pre-swizzled src
  const int kSrc = (((l & 7) ^ (l >> 3)) << 4);
  const char* gaA[4];
  const char* gaB[4];
  uint32_t lofs[4];
#pragma unroll
  for (int i = 0; i < 4; i++) {
    int c = i * 8 + w;              // 0..31
    int r = c * 8 + (l >> 3);       // 0..255
    int tk = stok[r]; if (tk < 0) tk = 0;
    gaA[i] = (const char*)(xbf + (size_t)tk * HDIM) + kSrc;
    gaB[i] = (const char*)(wbf + ((size_t)ge * DDIM + d0 + r) * HDIM) + kSrc;
    lofs[i] = (uint32_t)c * 1024;   // wave-uniform
  }

  const int wrow = w >> 2, wcol = w & 3;       // 2 x 4 wave grid
  const int arow = wrow * 128 + (l & 15);
  const int brow = wcol * 64 + (l & 15);
  const int swzr = (l & 7) << 4;               // row&7 == l&7 for frag rows
  const int koct = (l >> 4) * 16;

  f32x4 acc[8][4];
#pragma unroll
  for (int m = 0; m < 8; m++)
#pragma unroll
    for (int n = 0; n < 4; n++) acc[m][n] = (f32x4)0.f;

  for (int h = 0; h < HDIM * 2; h += 128) {    // 128 B = 64 bf16 per K-step
#pragma unroll
    for (int i = 0; i < 4; i++) gload16(gaA[i] + h, (char*)As + lofs[i]);
#pragma unroll
    for (int i = 0; i < 4; i++) gload16(gaB[i] + h, (char*)Bs + lofs[i]);
    __syncthreads();   // drains vmcnt

#pragma unroll
    for (int ks = 0; ks < 2; ks++) {
      const int kb = ks * 64 + koct;
      short8 b[4];
#pragma unroll
      for (int n = 0; n < 4; n++)
        b[n] = *(const short8*)((const char*)Bs + (brow + n * 16) * 128 + (kb ^ swzr));
#pragma unroll
      for (int m = 0; m < 8; m++) {
        short8 a = *(const short8*)((const char*)As + (arow + m * 16) * 128 + (kb ^ swzr));
#pragma unroll
        for (int n = 0; n < 4; n++)
          acc[m][n] = __builtin_amdgcn_mfma_f32_16x16x32_bf16(a, b[n], acc[m][n], 0, 0, 0);
      }
    }
    __syncthreads();
  }

  // epilogue: D row=(l>>4)*4+reg (token slot), col=l&15 (d)  [m89 layout]
#pragma unroll
  for (int m = 0; m < 8; m++) {
#pragma unroll
    for (int reg = 0; reg < 4; reg++) {
      int slot = wrow * 128 + m * 16 + (l >> 4) * 4 + reg;
      int tk = stok[slot];
      if (tk < 0) continue;
      float rwv = srw[slot] * 0.25f;
#pragma unroll
      for (int n = 0; n < 4; n++) {
        int d = d0 + wcol * 64 + n * 16 + (l & 15);
        float v = (acc[m][n][reg] + expert_b[ge * DDIM + d]) * rwv;
        atomicAdd(&avg_out[(size_t)tk * DDIM + d], v);
      }
    }
  }
}

// ---------------------------------------------------------------------------
// Final v2: out[t][j] = xorig[t][j] + orig_b[j] + avg[t]·agg_w[j] + agg_b[j]
// One wave per token; no x re-read.
// ---------------------------------------------------------------------------
__global__ __launch_bounds__(256) void final_kernel(
    const float* __restrict__ avg, const float* __restrict__ agg_w,
    const float* __restrict__ agg_b, const float* __restrict__ orig_b,
    const float* __restrict__ xorig, float* __restrict__ out) {
  const int w = threadIdx.x >> 6, lane = threadIdx.x & 63;
  const int t = blockIdx.x * 4 + w;
  const float4* av = (const float4*)(avg + (size_t)t * DDIM);
  float s[NGROUP];
#pragma unroll
  for (int j = 0; j < NGROUP; j++) {
    const float4* gv = (const float4*)(agg_w + j * DDIM);
    float acc = 0.f;
#pragma unroll
    for (int i = lane; i < DDIM / 4; i += 64) {
      float4 a = av[i], b = gv[i];
      acc += a.x * b.x + a.y * b.y + a.z * b.z + a.w * b.w;
    }
#pragma unroll
    for (int off = 32; off; off >>= 1) acc += __shfl_xor(acc, off);
    s[j] = acc;
  }
  if (lane == 0) {
    float4 o;
    o.x = s[0] + xorig[t * 4 + 0] + orig_b[0] + agg_b[0];
    o.y = s[1] + xorig[t * 4 + 1] + orig_b[1] + agg_b[1];
    o.z = s[2] + xorig[t * 4 + 2] + orig_b[2] + agg_b[2];
    o.w = s[3] + xorig[t * 4 + 3] + orig_b[3] + agg_b[3];
    *(float4*)(out + (size_t)t * NGROUP) = o;
  }
}

// ---------------------------------------------------------------------------
extern "C" void kernel_launch(void* const* d_in, const int* in_sizes, int n_in,
                              void* d_out, int out_size, void* d_ws, size_t ws_size,
                              hipStream_t stream) {
  const float* x        = (const float*)d_in[0];
  const float* gate_w   = (const float*)d_in[1];
  const float* expert_w = (const float*)d_in[2];
  const float* expert_b = (const float*)d_in[3];
  const float* agg_w    = (const float*)d_in[4];
  const float* agg_b    = (const float*)d_in[5];
  const float* orig_w   = (const float*)d_in[6];
  const float* orig_b   = (const float*)d_in[7];
  float* out = (float*)d_out;

  // workspace (~113.3 MiB): avg_out | xbf | wbf | counts | ltok | lw | xorig
  char* ws = (char*)d_ws;
  float*  avg_out = (float*)ws;                                  // 16 MiB
  ushort* xbf     = (ushort*)(ws + (size_t)16 * 1024 * 1024);    // 32 MiB
  ushort* wbf     = (ushort*)(ws + (size_t)48 * 1024 * 1024);    // 64 MiB
  int*    counts  = (int*)(ws + (size_t)112 * 1024 * 1024);
  int*    ltok    = counts + NGE;
  float*  lwt     = (float*)(ltok + NGE * CAP);
  float*  xorig   = lwt + NGE * CAP;                             // 128 KiB

  hipMemsetAsync(counts, 0, NGE * sizeof(int), stream);
  hipMemsetAsync(avg_out, 0, (size_t)T_TOK * DDIM * sizeof(float), stream);

  convert_w<<<(NGE * DDIM * HDIM) / (256 * 8), 256, 0, stream>>>(expert_w, wbf);
  gating_kernel<<<T_TOK / 8, 256, 0, stream>>>(x, gate_w, orig_w, counts, ltok, lwt, xbf, xorig);

  expert_gemm_bf16<<<NGE * 16 * 2, 512, 0, stream>>>(xbf, wbf, expert_b, counts, ltok, lwt, avg_out);

  final_kernel<<<T_TOK / 4, 256, 0, stream>>>(avg_out, agg_w, agg_b, orig_b, xorig, out);
}

// Round 6
// 633.010 us; speedup vs baseline: 3.0546x; 3.0546x over previous
//
#include <hip/hip_runtime.h>
#include <hip/hip_bf16.h>

// Problem constants: B=4,S=2048,H=2048,G=4,E=8,D=512,TOP_K=2
#define T_TOK   8192
#define HDIM    2048
#define DDIM    512
#define NGROUP  4
#define NEXP    8
#define NGE     32

// ---------------------------------------------------------------------------
// Algebraic collapse: final[t,j] = orig[t,j] + agg_b[j]
//   + 0.25 * sum_{g, sel} w_sel * ( x_t · V[ge_sel][j] + c[ge_sel][j] )
// where V[ge][j][h] = sum_d expert_w[ge][d][h] * agg_w[j][d]   (1 MB table)
//       c[ge][j]    = sum_d expert_b[ge][d]    * agg_w[j][d]
// The 137-GFLOP expert GEMM and all scatter/atomic machinery vanish.
// ---------------------------------------------------------------------------

// ---------------------------------------------------------------------------
// Kernel 1: V precompute. Grid (ge=32, dchunk=8); each block reduces 64 d-rows
// of expert_w[ge] (512 KB, coalesced float4x2 per thread) into 4x8 register
// accumulators, then atomicAdd into V (zeroed; 8-way contention only).
// Also reduces c[ge][j] (wave j handles j).
// ---------------------------------------------------------------------------
__global__ __launch_bounds__(256) void compute_v(
    const float* __restrict__ expert_w, const float* __restrict__ expert_b,
    const float* __restrict__ agg_w, float* __restrict__ V,
    float* __restrict__ c_arr) {
  const int ge = blockIdx.x;
  const int dc = blockIdx.y;          // 8 chunks x 64 d
  const int tid = threadIdx.x;

  __shared__ float a_s[NGROUP][64];   // agg_w chunk
  __shared__ float b_s[64];           // expert_b chunk
  {
    int j = tid >> 6, dd = tid & 63;
    a_s[j][dd] = agg_w[j * DDIM + dc * 64 + dd];
    if (tid < 64) b_s[tid] = expert_b[ge * DDIM + dc * 64 + tid];
  }
  __syncthreads();

  const float* wbase = expert_w + ((size_t)ge * DDIM + dc * 64) * HDIM + tid * 8;
  float acc[NGROUP][8];
#pragma unroll
  for (int j = 0; j < NGROUP; j++)
#pragma unroll
    for (int o = 0; o < 8; o++) acc[j][o] = 0.f;

  for (int dd = 0; dd < 64; dd++) {
    const float4* p = (const float4*)(wbase + (size_t)dd * HDIM);
    float4 f0 = p[0], f1 = p[1];
    float f[8] = {f0.x, f0.y, f0.z, f0.w, f1.x, f1.y, f1.z, f1.w};
#pragma unroll
    for (int j = 0; j < NGROUP; j++) {
      float a = a_s[j][dd];
#pragma unroll
      for (int o = 0; o < 8; o++) acc[j][o] += a * f[o];
    }
  }

#pragma unroll
  for (int j = 0; j < NGROUP; j++)
#pragma unroll
    for (int o = 0; o < 8; o++)
      atomicAdd(&V[((size_t)(ge * NGROUP + j)) * HDIM + tid * 8 + o], acc[j][o]);

  // c[ge][j]: wave w == j reduces b_s . a_s[j]
  {
    const int w = tid >> 6, lane = tid & 63;
    float cv = b_s[lane] * a_s[w][lane];
#pragma unroll
    for (int off = 32; off; off >>= 1) cv += __shfl_xor(cv, off);
    if (lane == 0) atomicAdd(&c_arr[ge * NGROUP + w], cv);
  }
}

// ---------------------------------------------------------------------------
// Kernel 2: fully fused MoE. 8 tokens/block, 256 thr. Wave g handles group g:
//   phase A: 9 dots/token (8 gate logits + orig_w[g]) - identical arithmetic
//            order to the round-4/5 passing kernel -> same routing decisions.
//   select : lanes 0..7 pick top-2 (first-index tie-break), w0=1/(1+e^(l1-l0)).
//   phase B: per token, 8-lane groups each compute one x.V[ge_sel][j] dot
//            (V is L2-resident, 1 MB); group shuffle-reduce; +c; *w; pair-sum.
//   writer : out[t][j] = sum_g pacc + porig[j] + orig_b[j] + agg_b[j].
// x is read exactly once across the whole pipeline.
// ---------------------------------------------------------------------------
__global__ __launch_bounds__(256) void fused_moe(
    const float* __restrict__ x, const float* __restrict__ gate_w,
    const float* __restrict__ orig_w, const float* __restrict__ V,
    const float* __restrict__ c_arr, const float* __restrict__ agg_b,
    const float* __restrict__ orig_b, float* __restrict__ out) {
  const int t0 = blockIdx.x * 8;
  __shared__ float xsm[8 * HDIM];             // 64 KiB
  __shared__ float pacc[NGROUP][8][NGROUP];   // per-wave V contributions
  __shared__ float porig[NGROUP][8];          // x . orig_w[g]
  const int tid = threadIdx.x;

  // stage 8 token rows (coalesced)
  {
    const int r = tid >> 5, ci = tid & 31;
    const float4* xrow = (const float4*)(x + (size_t)(t0 + r) * HDIM);
    float4* xsrow = (float4*)(xsm + r * HDIM);
#pragma unroll
    for (int q = 0; q < 16; q++) xsrow[ci + 32 * q] = xrow[ci + 32 * q];
  }
  __syncthreads();

  const int g = tid >> 6, lane = tid & 63;
  const float4* xs4 = (const float4*)xsm;

  // ---- phase A: gate logits + orig dot ----
  float logits[NEXP];
  float ov = 0.f;
#pragma unroll
  for (int e = 0; e < 9; e++) {
    const float* wrow = (e < 8) ? (gate_w + ((size_t)g * NEXP + e) * HDIM)
                                : (orig_w + (size_t)g * HDIM);
    const float4* gv = (const float4*)wrow;
    float s[8];
#pragma unroll
    for (int k = 0; k < 8; k++) s[k] = 0.f;
#pragma unroll
    for (int i = lane; i < HDIM / 4; i += 64) {
      float4 b = gv[i];
#pragma unroll
      for (int k = 0; k < 8; k++) {
        float4 a = xs4[k * (HDIM / 4) + i];
        s[k] += a.x * b.x + a.y * b.y + a.z * b.z + a.w * b.w;
      }
    }
#pragma unroll
    for (int k = 0; k < 8; k++)
#pragma unroll
      for (int off = 32; off; off >>= 1) s[k] += __shfl_xor(s[k], off);
    float lg = s[0];
#pragma unroll
    for (int k = 1; k < 8; k++) lg = (lane == k) ? s[k] : lg;
    if (e < 8) logits[e] = lg; else ov = lg;
  }

  // ---- selection (lanes 0..7; lane = token slot) ----
  int ge0v = 0, ge1v = 0; float w0v = 0.f, w1v = 0.f;
  if (lane < 8) {
    porig[g][lane] = ov;
    int i0 = 0; float l0 = logits[0];
#pragma unroll
    for (int e = 1; e < NEXP; e++)
      if (logits[e] > l0) { l0 = logits[e]; i0 = e; }
    int i1 = -1; float l1 = -1e30f;
#pragma unroll
    for (int e = 0; e < NEXP; e++) {
      if (e == i0) continue;
      if (logits[e] > l1) { l1 = logits[e]; i1 = e; }
    }
    w0v = 1.f / (1.f + expf(l1 - l0));   // softmax->top2->renorm, exact
    w1v = 1.f - w0v;
    ge0v = (g << 3) + i0;
    ge1v = (g << 3) + i1;
  }

  // ---- phase B: selected V dots; 8-lane group 'grp' owns one (sel,j) row ----
  const int sub = lane & 7;
  const int grp = lane >> 3;
  const int jr = grp & 3;
  for (int tk = 0; tk < 8; tk++) {
    const int ge0 = __shfl(ge0v, tk);
    const int ge1 = __shfl(ge1v, tk);
    const float w0 = __shfl(w0v, tk);
    const float w1 = __shfl(w1v, tk);
    const int gesel = (lane < 32) ? ge0 : ge1;
    const float4* vrow = (const float4*)(V + ((size_t)gesel * NGROUP + jr) * HDIM);
    const float4* xr = (const float4*)(xsm + tk * HDIM);
    float s0 = 0.f, s1 = 0.f;
#pragma unroll 8
    for (int k = 0; k < 64; k += 2) {
      float4 a0 = xr[sub + k * 8],       b0 = vrow[sub + k * 8];
      float4 a1 = xr[sub + (k + 1) * 8], b1 = vrow[sub + (k + 1) * 8];
      s0 += a0.x * b0.x + a0.y * b0.y + a0.z * b0.z + a0.w * b0.w;
      s1 += a1.x * b1.x + a1.y * b1.y + a1.z * b1.z + a1.w * b1.w;
    }
    float s = s0 + s1;
    s += __shfl_xor(s, 1); s += __shfl_xor(s, 2); s += __shfl_xor(s, 4);
    float z = (s + c_arr[gesel * NGROUP + jr]) * ((lane < 32) ? w0 : w1);
    z += __shfl_xor(z, 32);              // lane 8j += lane 8j+32  (sel0 + sel1)
    if (lane < 32 && sub == 0) pacc[g][tk][grp] = 0.25f * z;
  }
  __syncthreads();

  // ---- writer ----
  if (tid < 32) {
    const int tk = tid >> 2, j = tid & 3;
    float v = pacc[0][tk][j] + pacc[1][tk][j] + pacc[2][tk][j] + pacc[3][tk][j]
            + porig[j][tk] + orig_b[j] + agg_b[j];
    out[(size_t)(t0 + tk) * NGROUP + j] = v;
  }
}

// ---------------------------------------------------------------------------
extern "C" void kernel_launch(void* const* d_in, const int* in_sizes, int n_in,
                              void* d_out, int out_size, void* d_ws, size_t ws_size,
                              hipStream_t stream) {
  const float* x        = (const float*)d_in[0];
  const float* gate_w   = (const float*)d_in[1];
  const float* expert_w = (const float*)d_in[2];
  const float* expert_b = (const float*)d_in[3];
  const float* agg_w    = (const float*)d_in[4];
  const float* agg_b    = (const float*)d_in[5];
  const float* orig_w   = (const float*)d_in[6];
  const float* orig_b   = (const float*)d_in[7];
  float* out = (float*)d_out;

  // workspace: V (1 MiB) | c (512 B)
  float* V     = (float*)d_ws;
  float* c_arr = V + (size_t)NGE * NGROUP * HDIM;

  hipMemsetAsync(V, 0, (size_t)(NGE * NGROUP * HDIM + NGE * NGROUP) * sizeof(float), stream);

  dim3 vg(NGE, 8);
  compute_v<<<vg, 256, 0, stream>>>(expert_w, expert_b, agg_w, V, c_arr);

  fused_moe<<<T_TOK / 8, 256, 0, stream>>>(x, gate_w, orig_w, V, c_arr,
                                           agg_b, orig_b, out);
}

// Round 7
// 556.596 us; speedup vs baseline: 3.4740x; 1.1373x over previous
//
#include <hip/hip_runtime.h>
#include <hip/hip_bf16.h>

// Problem constants: B=4,S=2048,H=2048,G=4,E=8,D=512,TOP_K=2
#define T_TOK   8192
#define HDIM    2048
#define DDIM    512
#define NGROUP  4
#define NEXP    8
#define NGE     32
#define NV      (NGE * NGROUP)   // 128 V rows

typedef __attribute__((ext_vector_type(8))) short short8;
typedef __attribute__((ext_vector_type(4))) float f32x4;

struct alignas(16) U8 { ushort u[8]; };
struct alignas(8)  U4 { ushort u[4]; };

__device__ __forceinline__ ushort f2bf(float f) {
  union { __hip_bfloat16 h; ushort u; } c;
  c.h = __float2bfloat16(f);
  return c.u;
}

__device__ __forceinline__ void gload16(const void* g, void* l) {
  __builtin_amdgcn_global_load_lds(
      (const __attribute__((address_space(1))) void*)g,
      (__attribute__((address_space(3))) void*)l, 16, 0, 0);
}

// ---------------------------------------------------------------------------
// K1: V[ge*4+j][h] = sum_d expert_w[ge][d][h] * agg_w[j][d];  c = b . agg_w.
// Grid (32 ge, 32 dchunks of 16 d-rows) = 1024 blocks (4/CU, fixes the round-6
// 1-block/CU latency bind). Coalesced 32B/thread rows, acc in regs, atomics out.
// ---------------------------------------------------------------------------
__global__ __launch_bounds__(256) void compute_v(
    const float* __restrict__ expert_w, const float* __restrict__ expert_b,
    const float* __restrict__ agg_w, float* __restrict__ V,
    float* __restrict__ c_arr) {
  const int ge = blockIdx.x;
  const int dc = blockIdx.y;          // 16 d-rows per chunk
  const int tid = threadIdx.x;

  __shared__ float a_s[NGROUP][16];
  __shared__ float b_s[16];
  if (tid < 64) {
    int j = tid >> 4, dd = tid & 15;
    a_s[j][dd] = agg_w[j * DDIM + dc * 16 + dd];
    if (j == 0) b_s[dd] = expert_b[ge * DDIM + dc * 16 + dd];
  }
  __syncthreads();

  const float* wbase = expert_w + ((size_t)ge * DDIM + dc * 16) * HDIM + tid * 8;
  float acc[NGROUP][8];
#pragma unroll
  for (int j = 0; j < NGROUP; j++)
#pragma unroll
    for (int o = 0; o < 8; o++) acc[j][o] = 0.f;

#pragma unroll 2
  for (int dd = 0; dd < 16; dd++) {
    const float4* p = (const float4*)(wbase + (size_t)dd * HDIM);
    float4 f0 = p[0], f1 = p[1];
    float f[8] = {f0.x, f0.y, f0.z, f0.w, f1.x, f1.y, f1.z, f1.w};
#pragma unroll
    for (int j = 0; j < NGROUP; j++) {
      float a = a_s[j][dd];
#pragma unroll
      for (int o = 0; o < 8; o++) acc[j][o] += a * f[o];
    }
  }

#pragma unroll
  for (int j = 0; j < NGROUP; j++)
#pragma unroll
    for (int o = 0; o < 8; o++)
      atomicAdd(&V[((size_t)(ge * NGROUP + j)) * HDIM + tid * 8 + o], acc[j][o]);

  if (tid < 64) {
    int j = tid >> 4, dd = tid & 15;
    float v = b_s[dd] * a_s[j][dd];
    v += __shfl_xor(v, 1); v += __shfl_xor(v, 2);
    v += __shfl_xor(v, 4); v += __shfl_xor(v, 8);
    if (dd == 0) atomicAdd(&c_arr[ge * NGROUP + j], v);
  }
}

// ---------------------------------------------------------------------------
// K1b: V fp32 -> bf16
// ---------------------------------------------------------------------------
__global__ __launch_bounds__(256) void convert_vbf(
    const float* __restrict__ V, ushort* __restrict__ vbf) {
  const int i = (blockIdx.x * 256 + threadIdx.x) * 8;
  float4 f0 = *(const float4*)(V + i);
  float4 f1 = *(const float4*)(V + i + 4);
  U8 p;
  p.u[0] = f2bf(f0.x); p.u[1] = f2bf(f0.y); p.u[2] = f2bf(f0.z); p.u[3] = f2bf(f0.w);
  p.u[4] = f2bf(f1.x); p.u[5] = f2bf(f1.y); p.u[6] = f2bf(f1.z); p.u[7] = f2bf(f1.w);
  *(U8*)(vbf + i) = p;
}

// ---------------------------------------------------------------------------
// K2: gating. Round-5/6 phase-A arithmetic EXACTLY (same logits bitwise ->
// same routing as the passing kernels). e-loop kept as a runtime loop
// (#pragma unroll 1) to keep VGPR low — no phase B in this kernel.
// Writes: xbf (bf16 x), xorig, per-(t,g) selections + weights.
// ---------------------------------------------------------------------------
__global__ __launch_bounds__(256) void gating_kernel(
    const float* __restrict__ x, const float* __restrict__ gate_w,
    const float* __restrict__ orig_w, ushort* __restrict__ xbf,
    float* __restrict__ xorig, int2* __restrict__ sge,
    float2* __restrict__ swt) {
  const int t0 = blockIdx.x * 8;
  __shared__ float xsm[8 * HDIM];   // 64 KiB
  const int tid = threadIdx.x;

  {
    const int r = tid >> 5, ci = tid & 31;
    const float4* xrow = (const float4*)(x + (size_t)(t0 + r) * HDIM);
    float4* xsrow = (float4*)(xsm + r * HDIM);
    ushort* xbrow = xbf + (size_t)(t0 + r) * HDIM;
#pragma unroll
    for (int q = 0; q < 16; q++) {
      int idx = ci + 32 * q;
      float4 v = xrow[idx];
      xsrow[idx] = v;
      U4 p; p.u[0] = f2bf(v.x); p.u[1] = f2bf(v.y);
      p.u[2] = f2bf(v.z); p.u[3] = f2bf(v.w);
      *(U4*)(xbrow + idx * 4) = p;
    }
  }
  __syncthreads();

  const int g = tid >> 6, lane = tid & 63;
  const float4* xs4 = (const float4*)xsm;

  float logits[NEXP];
  float ov = 0.f;
#pragma unroll 1
  for (int e = 0; e < 9; e++) {
    const float* wrow = (e < 8) ? (gate_w + ((size_t)g * NEXP + e) * HDIM)
                                : (orig_w + (size_t)g * HDIM);
    const float4* gv = (const float4*)wrow;
    float s[8];
#pragma unroll
    for (int k = 0; k < 8; k++) s[k] = 0.f;
#pragma unroll 2
    for (int i = lane; i < HDIM / 4; i += 64) {
      float4 b = gv[i];
#pragma unroll
      for (int k = 0; k < 8; k++) {
        float4 a = xs4[k * (HDIM / 4) + i];
        s[k] += a.x * b.x + a.y * b.y + a.z * b.z + a.w * b.w;
      }
    }
#pragma unroll
    for (int k = 0; k < 8; k++)
#pragma unroll
      for (int off = 32; off; off >>= 1) s[k] += __shfl_xor(s[k], off);
    float lg = s[0];
#pragma unroll
    for (int k = 1; k < 8; k++) lg = (lane == k) ? s[k] : lg;
    if (e < 8) logits[e] = lg; else ov = lg;
  }

  if (lane < 8) {
    const int t = t0 + lane;
    xorig[t * NGROUP + g] = ov;
    int i0 = 0; float l0 = logits[0];
#pragma unroll
    for (int e = 1; e < NEXP; e++)
      if (logits[e] > l0) { l0 = logits[e]; i0 = e; }
    int i1 = -1; float l1 = -1e30f;
#pragma unroll
    for (int e = 0; e < NEXP; e++) {
      if (e == i0) continue;
      if (logits[e] > l1) { l1 = logits[e]; i1 = e; }
    }
    float w0 = 1.f / (1.f + expf(l1 - l0));   // softmax->top2->renorm, exact
    sge[t * NGROUP + g] = make_int2((g << 3) + i0, (g << 3) + i1);
    swt[t * NGROUP + g] = make_float2(w0, 1.f - w0);
  }
}

// ---------------------------------------------------------------------------
// K3: dense Y = xbf @ Vbf^T  (Y[8192][128], K=2048 split over 4 k-chunks).
// Round-4-verified 128x128 MFMA tile: 4 waves (2x2, 64x64 each), BK=64,
// both-sides XOR swizzle (bank-conflict-free, verified 0 on HW), linear LDS
// dest for global_load_lds. No gather (tokens sequential), atomicAdd into Y.
// ---------------------------------------------------------------------------
__global__ __launch_bounds__(256, 4) void ygemm(
    const ushort* __restrict__ xbf, const ushort* __restrict__ vbf,
    float* __restrict__ Y) {
  const int t0 = blockIdx.x * 128;
  const int kc = blockIdx.y;          // 4 chunks of 512 elems (1024 B)

  __shared__ ushort As[128 * 64];
  __shared__ ushort Bs[128 * 64];

  const int tid = threadIdx.x;
  const int w = tid >> 6, l = tid & 63;

  const int kSrc = (((l & 7) ^ (l >> 3)) << 4);
  const char* gaA[4];
  const char* gaB[4];
  uint32_t lofs[4];
#pragma unroll
  for (int i = 0; i < 4; i++) {
    int c = i * 4 + w;
    int r = c * 8 + (l >> 3);
    gaA[i] = (const char*)(xbf + (size_t)(t0 + r) * HDIM) + kSrc;
    gaB[i] = (const char*)(vbf + (size_t)r * HDIM) + kSrc;
    lofs[i] = (uint32_t)c * 1024;
  }

  const int wr = w >> 1, wc = w & 1;
  const int arow = wr * 64 + (l & 15);
  const int brow = wc * 64 + (l & 15);
  const int swz = (l & 7) << 4;
  const int koct = (l >> 4) * 16;

  f32x4 acc[4][4];
#pragma unroll
  for (int m = 0; m < 4; m++)
#pragma unroll
    for (int n = 0; n < 4; n++) acc[m][n] = (f32x4)0.f;

  for (int h = kc * 1024; h < kc * 1024 + 1024; h += 128) {
#pragma unroll
    for (int i = 0; i < 4; i++) gload16(gaA[i] + h, (char*)As + lofs[i]);
#pragma unroll
    for (int i = 0; i < 4; i++) gload16(gaB[i] + h, (char*)Bs + lofs[i]);
    __syncthreads();

#pragma unroll
    for (int ks = 0; ks < 2; ks++) {
      const int kb = ks * 64 + koct;
      short8 a[4], b[4];
#pragma unroll
      for (int m = 0; m < 4; m++)
        a[m] = *(const short8*)((const char*)As + (arow + m * 16) * 128 + (kb ^ swz));
#pragma unroll
      for (int n = 0; n < 4; n++)
        b[n] = *(const short8*)((const char*)Bs + (brow + n * 16) * 128 + (kb ^ swz));
#pragma unroll
      for (int m = 0; m < 4; m++)
#pragma unroll
        for (int n = 0; n < 4; n++)
          acc[m][n] = __builtin_amdgcn_mfma_f32_16x16x32_bf16(a[m], b[n], acc[m][n], 0, 0, 0);
    }
    __syncthreads();
  }

#pragma unroll
  for (int m = 0; m < 4; m++)
#pragma unroll
    for (int reg = 0; reg < 4; reg++) {
      int slot = wr * 64 + m * 16 + (l >> 4) * 4 + reg;
#pragma unroll
      for (int n = 0; n < 4; n++) {
        int col = wc * 64 + n * 16 + (l & 15);
        atomicAdd(&Y[(size_t)(t0 + slot) * NV + col], acc[m][n][reg]);
      }
    }
}

// ---------------------------------------------------------------------------
// K4: combine. out[t][j] = 0.25*sum_{g,sel} w*(Y[t][ge*4+j] + c[ge*4+j])
//                          + xorig[t][j] + orig_b[j] + agg_b[j]
// ---------------------------------------------------------------------------
__global__ __launch_bounds__(256) void combine_kernel(
    const float* __restrict__ Y, const float* __restrict__ c_arr,
    const int2* __restrict__ sge, const float2* __restrict__ swt,
    const float* __restrict__ xorig, const float* __restrict__ orig_b,
    const float* __restrict__ agg_b, float* __restrict__ out) {
  const int tid = threadIdx.x;
  const int t = blockIdx.x * 64 + (tid >> 2);
  const int j = tid & 3;
  const float* yrow = Y + (size_t)t * NV;
  float acc = 0.f;
#pragma unroll
  for (int g = 0; g < NGROUP; g++) {
    int2 sel = sge[t * NGROUP + g];
    float2 wv = swt[t * NGROUP + g];
    acc += wv.x * (yrow[sel.x * 4 + j] + c_arr[sel.x * 4 + j]);
    acc += wv.y * (yrow[sel.y * 4 + j] + c_arr[sel.y * 4 + j]);
  }
  out[(size_t)t * NGROUP + j] = 0.25f * acc + xorig[t * NGROUP + j]
                              + orig_b[j] + agg_b[j];
}

// ---------------------------------------------------------------------------
extern "C" void kernel_launch(void* const* d_in, const int* in_sizes, int n_in,
                              void* d_out, int out_size, void* d_ws, size_t ws_size,
                              hipStream_t stream) {
  const float* x        = (const float*)d_in[0];
  const float* gate_w   = (const float*)d_in[1];
  const float* expert_w = (const float*)d_in[2];
  const float* expert_b = (const float*)d_in[3];
  const float* agg_w    = (const float*)d_in[4];
  const float* agg_b    = (const float*)d_in[5];
  const float* orig_w   = (const float*)d_in[6];
  const float* orig_b   = (const float*)d_in[7];
  float* out = (float*)d_out;

  // workspace (~40 MiB): V | Vbf | c | xorig | sge | swt | xbf | Y
  char* ws = (char*)d_ws;
  const size_t MB = 1024 * 1024;
  float*  V     = (float*)ws;                       // 1 MiB
  ushort* vbf   = (ushort*)(ws + 1 * MB);           // 0.5 MiB
  float*  c_arr = (float*)(ws + 1536 * 1024);       // 512 B
  float*  xorig = (float*)(ws + 2 * MB);            // 128 KiB
  int2*   sge   = (int2*)(ws + 3 * MB);             // 256 KiB
  float2* swt   = (float2*)(ws + 3 * MB + 512 * 1024);  // 256 KiB
  ushort* xbf   = (ushort*)(ws + 4 * MB);           // 32 MiB
  float*  Y     = (float*)(ws + 36 * MB);           // 4 MiB

  hipMemsetAsync(ws, 0, 2 * MB, stream);                        // V, vbf, c
  hipMemsetAsync(Y, 0, (size_t)T_TOK * NV * sizeof(float), stream);

  dim3 vg(NGE, 32);
  compute_v<<<vg, 256, 0, stream>>>(expert_w, expert_b, agg_w, V, c_arr);
  gating_kernel<<<T_TOK / 8, 256, 0, stream>>>(x, gate_w, orig_w, xbf, xorig, sge, swt);
  convert_vbf<<<NV * HDIM / 2048, 256, 0, stream>>>(V, vbf);

  dim3 yg(T_TOK / 128, 4);
  ygemm<<<yg, 256, 0, stream>>>(xbf, vbf, Y);

  combine_kernel<<<T_TOK / 64, 256, 0, stream>>>(Y, c_arr, sge, swt, xorig,
                                                 orig_b, agg_b, out);
}

// Round 8
// 332.196 us; speedup vs baseline: 5.8207x; 1.6755x over previous
//
#include <hip/hip_runtime.h>
#include <hip/hip_bf16.h>

// Problem constants: B=4,S=2048,H=2048,G=4,E=8,D=512,TOP_K=2
#define T_TOK   8192
#define HDIM    2048
#define DDIM    512
#define NGROUP  4
#define NEXP    8
#define NGE     32
#define NV      (NGE * NGROUP)   // 128 V rows

typedef __attribute__((ext_vector_type(8))) short short8;
typedef __attribute__((ext_vector_type(4))) float f32x4;

struct alignas(16) U8 { ushort u[8]; };
struct alignas(8)  U4 { ushort u[4]; };

__device__ __forceinline__ ushort f2bf(float f) {
  union { __hip_bfloat16 h; ushort u; } c;
  c.h = __float2bfloat16(f);
  return c.u;
}

__device__ __forceinline__ void gload16(const void* g, void* l) {
  __builtin_amdgcn_global_load_lds(
      (const __attribute__((address_space(1))) void*)g,
      (__attribute__((address_space(3))) void*)l, 16, 0, 0);
}

// ---------------------------------------------------------------------------
// K1: V partials, ATOMIC-FREE (round-7 compute_v wrote 262MB of atomic
// ping-pong through HBM). Grid (ge=32, hc=8, dz=4) = 1024 blocks; each block
// reduces 128 d-rows over a 256-float h-chunk in registers, LDS-reduces the
// 4 sub-d groups, writes its private partial slice once (coalesced).
// ---------------------------------------------------------------------------
__global__ __launch_bounds__(256) void compute_v_part(
    const float* __restrict__ expert_w, const float* __restrict__ agg_w,
    float* __restrict__ Vp) {
  const int ge = blockIdx.x;
  const int hc = blockIdx.y;          // 8 chunks x 256 floats (64 float4)
  const int dz = blockIdx.z;          // 4 chunks x 128 d-rows
  const int tid = threadIdx.x;
  const int h4 = tid & 63;            // float4 index within chunk
  const int dq = tid >> 6;            // sub-d group (32 rows each)
  const int d0 = dz * 128;

  __shared__ float a_s[NGROUP][128];
  __shared__ float4 red[4][64][NGROUP];
  for (int i = tid; i < NGROUP * 128; i += 256) {
    int j = i >> 7, dd = i & 127;
    a_s[j][dd] = agg_w[j * DDIM + d0 + dd];
  }
  __syncthreads();

  const float* wbase = expert_w
      + ((size_t)(ge * DDIM) + d0 + dq * 32) * HDIM + hc * 256 + h4 * 4;
  float4 acc[NGROUP];
#pragma unroll
  for (int j = 0; j < NGROUP; j++) acc[j] = make_float4(0.f, 0.f, 0.f, 0.f);

#pragma unroll 4
  for (int dd = 0; dd < 32; dd++) {
    float4 f = *(const float4*)(wbase + (size_t)dd * HDIM);
#pragma unroll
    for (int j = 0; j < NGROUP; j++) {
      float a = a_s[j][dq * 32 + dd];
      acc[j].x += a * f.x; acc[j].y += a * f.y;
      acc[j].z += a * f.z; acc[j].w += a * f.w;
    }
  }

#pragma unroll
  for (int j = 0; j < NGROUP; j++) red[dq][h4][j] = acc[j];
  __syncthreads();

  {
    const int oh = tid & 63, oj = tid >> 6;
    float4 s0 = red[0][oh][oj], s1 = red[1][oh][oj];
    float4 s2 = red[2][oh][oj], s3 = red[3][oh][oj];
    float4 s = make_float4(s0.x + s1.x + s2.x + s3.x,
                           s0.y + s1.y + s2.y + s3.y,
                           s0.z + s1.z + s2.z + s3.z,
                           s0.w + s1.w + s2.w + s3.w);
    *(float4*)(Vp + ((size_t)dz * NV + ge * NGROUP + oj) * HDIM
               + hc * 256 + oh * 4) = s;
  }
}

// ---------------------------------------------------------------------------
// K1b: reduce 4 partials -> bf16 V (fused convert; no fp32 V materialized)
// ---------------------------------------------------------------------------
__global__ __launch_bounds__(256) void reduce_v(
    const float* __restrict__ Vp, ushort* __restrict__ vbf) {
  const size_t i = ((size_t)blockIdx.x * 256 + threadIdx.x) * 8;
  const size_t N = (size_t)NV * HDIM;
  float s[8];
#pragma unroll
  for (int o = 0; o < 8; o++) s[o] = 0.f;
#pragma unroll
  for (int p = 0; p < 4; p++) {
    float4 f0 = *(const float4*)(Vp + p * N + i);
    float4 f1 = *(const float4*)(Vp + p * N + i + 4);
    s[0] += f0.x; s[1] += f0.y; s[2] += f0.z; s[3] += f0.w;
    s[4] += f1.x; s[5] += f1.y; s[6] += f1.z; s[7] += f1.w;
  }
  U8 pk;
#pragma unroll
  for (int o = 0; o < 8; o++) pk.u[o] = f2bf(s[o]);
  *(U8*)(vbf + i) = pk;
}

// ---------------------------------------------------------------------------
// K1c: c[ge][j] = expert_b[ge] . agg_w[j]  (atomic-free, 32 blocks)
// ---------------------------------------------------------------------------
__global__ __launch_bounds__(256) void compute_c(
    const float* __restrict__ expert_b, const float* __restrict__ agg_w,
    float* __restrict__ c_arr) {
  const int ge = blockIdx.x;
  const int j = threadIdx.x >> 6, lane = threadIdx.x & 63;
  const float4* b4 = (const float4*)(expert_b + ge * DDIM);
  const float4* a4 = (const float4*)(agg_w + j * DDIM);
  float s = 0.f;
#pragma unroll
  for (int q = 0; q < 2; q++) {
    int idx = lane + 64 * q;
    float4 b = b4[idx], a = a4[idx];
    s += b.x * a.x + b.y * a.y + b.z * a.z + b.w * a.w;
  }
#pragma unroll
  for (int off = 32; off; off >>= 1) s += __shfl_xor(s, off);
  if (lane == 0) c_arr[ge * NGROUP + j] = s;
}

// ---------------------------------------------------------------------------
// K2: gating — identical arithmetic to rounds 5-7 (bitwise-same routing).
// Writes xbf (bf16 x), xorig, selections + weights.
// ---------------------------------------------------------------------------
__global__ __launch_bounds__(256) void gating_kernel(
    const float* __restrict__ x, const float* __restrict__ gate_w,
    const float* __restrict__ orig_w, ushort* __restrict__ xbf,
    float* __restrict__ xorig, int2* __restrict__ sge,
    float2* __restrict__ swt) {
  const int t0 = blockIdx.x * 8;
  __shared__ float xsm[8 * HDIM];   // 64 KiB
  const int tid = threadIdx.x;

  {
    const int r = tid >> 5, ci = tid & 31;
    const float4* xrow = (const float4*)(x + (size_t)(t0 + r) * HDIM);
    float4* xsrow = (float4*)(xsm + r * HDIM);
    ushort* xbrow = xbf + (size_t)(t0 + r) * HDIM;
#pragma unroll
    for (int q = 0; q < 16; q++) {
      int idx = ci + 32 * q;
      float4 v = xrow[idx];
      xsrow[idx] = v;
      U4 p; p.u[0] = f2bf(v.x); p.u[1] = f2bf(v.y);
      p.u[2] = f2bf(v.z); p.u[3] = f2bf(v.w);
      *(U4*)(xbrow + idx * 4) = p;
    }
  }
  __syncthreads();

  const int g = tid >> 6, lane = tid & 63;
  const float4* xs4 = (const float4*)xsm;

  float logits[NEXP];
  float ov = 0.f;
#pragma unroll 1
  for (int e = 0; e < 9; e++) {
    const float* wrow = (e < 8) ? (gate_w + ((size_t)g * NEXP + e) * HDIM)
                                : (orig_w + (size_t)g * HDIM);
    const float4* gv = (const float4*)wrow;
    float s[8];
#pragma unroll
    for (int k = 0; k < 8; k++) s[k] = 0.f;
#pragma unroll 2
    for (int i = lane; i < HDIM / 4; i += 64) {
      float4 b = gv[i];
#pragma unroll
      for (int k = 0; k < 8; k++) {
        float4 a = xs4[k * (HDIM / 4) + i];
        s[k] += a.x * b.x + a.y * b.y + a.z * b.z + a.w * b.w;
      }
    }
#pragma unroll
    for (int k = 0; k < 8; k++)
#pragma unroll
      for (int off = 32; off; off >>= 1) s[k] += __shfl_xor(s[k], off);
    float lg = s[0];
#pragma unroll
    for (int k = 1; k < 8; k++) lg = (lane == k) ? s[k] : lg;
    if (e < 8) logits[e] = lg; else ov = lg;
  }

  if (lane < 8) {
    const int t = t0 + lane;
    xorig[t * NGROUP + g] = ov;
    int i0 = 0; float l0 = logits[0];
#pragma unroll
    for (int e = 1; e < NEXP; e++)
      if (logits[e] > l0) { l0 = logits[e]; i0 = e; }
    int i1 = -1; float l1 = -1e30f;
#pragma unroll
    for (int e = 0; e < NEXP; e++) {
      if (e == i0) continue;
      if (logits[e] > l1) { l1 = logits[e]; i1 = e; }
    }
    float w0 = 1.f / (1.f + expf(l1 - l0));   // softmax->top2->renorm, exact
    sge[t * NGROUP + g] = make_int2((g << 3) + i0, (g << 3) + i1);
    swt[t * NGROUP + g] = make_float2(w0, 1.f - w0);
  }
}

// ---------------------------------------------------------------------------
// K3: dense Y = xbf @ Vbf^T (Y[8192][128], K split over 4 chunks).
// Round-4-verified 128x128 MFMA tile, both-sides XOR swizzle (0 conflicts on
// HW). atomicAdd into Y (16 MB total, acceptable).
// ---------------------------------------------------------------------------
__global__ __launch_bounds__(256, 4) void ygemm(
    const ushort* __restrict__ xbf, const ushort* __restrict__ vbf,
    float* __restrict__ Y) {
  const int t0 = blockIdx.x * 128;
  const int kc = blockIdx.y;          // 4 chunks of 512 elems (1024 B)

  __shared__ ushort As[128 * 64];
  __shared__ ushort Bs[128 * 64];

  const int tid = threadIdx.x;
  const int w = tid >> 6, l = tid & 63;

  const int kSrc = (((l & 7) ^ (l >> 3)) << 4);
  const char* gaA[4];
  const char* gaB[4];
  uint32_t lofs[4];
#pragma unroll
  for (int i = 0; i < 4; i++) {
    int c = i * 4 + w;
    int r = c * 8 + (l >> 3);
    gaA[i] = (const char*)(xbf + (size_t)(t0 + r) * HDIM) + kSrc;
    gaB[i] = (const char*)(vbf + (size_t)r * HDIM) + kSrc;
    lofs[i] = (uint32_t)c * 1024;
  }

  const int wr = w >> 1, wc = w & 1;
  const int arow = wr * 64 + (l & 15);
  const int brow = wc * 64 + (l & 15);
  const int swz = (l & 7) << 4;
  const int koct = (l >> 4) * 16;

  f32x4 acc[4][4];
#pragma unroll
  for (int m = 0; m < 4; m++)
#pragma unroll
    for (int n = 0; n < 4; n++) acc[m][n] = (f32x4)0.f;

  for (int h = kc * 1024; h < kc * 1024 + 1024; h += 128) {
#pragma unroll
    for (int i = 0; i < 4; i++) gload16(gaA[i] + h, (char*)As + lofs[i]);
#pragma unroll
    for (int i = 0; i < 4; i++) gload16(gaB[i] + h, (char*)Bs + lofs[i]);
    __syncthreads();

#pragma unroll
    for (int ks = 0; ks < 2; ks++) {
      const int kb = ks * 64 + koct;
      short8 a[4], b[4];
#pragma unroll
      for (int m = 0; m < 4; m++)
        a[m] = *(const short8*)((const char*)As + (arow + m * 16) * 128 + (kb ^ swz));
#pragma unroll
      for (int n = 0; n < 4; n++)
        b[n] = *(const short8*)((const char*)Bs + (brow + n * 16) * 128 + (kb ^ swz));
#pragma unroll
      for (int m = 0; m < 4; m++)
#pragma unroll
        for (int n = 0; n < 4; n++)
          acc[m][n] = __builtin_amdgcn_mfma_f32_16x16x32_bf16(a[m], b[n], acc[m][n], 0, 0, 0);
    }
    __syncthreads();
  }

#pragma unroll
  for (int m = 0; m < 4; m++)
#pragma unroll
    for (int reg = 0; reg < 4; reg++) {
      int slot = wr * 64 + m * 16 + (l >> 4) * 4 + reg;
#pragma unroll
      for (int n = 0; n < 4; n++) {
        int col = wc * 64 + n * 16 + (l & 15);
        atomicAdd(&Y[(size_t)(t0 + slot) * NV + col], acc[m][n][reg]);
      }
    }
}

// ---------------------------------------------------------------------------
// K4: combine. out[t][j] = 0.25*sum_{g,sel} w*(Y[t][ge*4+j] + c[ge*4+j])
//                          + xorig[t][j] + orig_b[j] + agg_b[j]
// ---------------------------------------------------------------------------
__global__ __launch_bounds__(256) void combine_kernel(
    const float* __restrict__ Y, const float* __restrict__ c_arr,
    const int2* __restrict__ sge, const float2* __restrict__ swt,
    const float* __restrict__ xorig, const float* __restrict__ orig_b,
    const float* __restrict__ agg_b, float* __restrict__ out) {
  const int tid = threadIdx.x;
  const int t = blockIdx.x * 64 + (tid >> 2);
  const int j = tid & 3;
  const float* yrow = Y + (size_t)t * NV;
  float acc = 0.f;
#pragma unroll
  for (int g = 0; g < NGROUP; g++) {
    int2 sel = sge[t * NGROUP + g];
    float2 wv = swt[t * NGROUP + g];
    acc += wv.x * (yrow[sel.x * 4 + j] + c_arr[sel.x * 4 + j]);
    acc += wv.y * (yrow[sel.y * 4 + j] + c_arr[sel.y * 4 + j]);
  }
  out[(size_t)t * NGROUP + j] = 0.25f * acc + xorig[t * NGROUP + j]
                              + orig_b[j] + agg_b[j];
}

// ---------------------------------------------------------------------------
extern "C" void kernel_launch(void* const* d_in, const int* in_sizes, int n_in,
                              void* d_out, int out_size, void* d_ws, size_t ws_size,
                              hipStream_t stream) {
  const float* x        = (const float*)d_in[0];
  const float* gate_w   = (const float*)d_in[1];
  const float* expert_w = (const float*)d_in[2];
  const float* expert_b = (const float*)d_in[3];
  const float* agg_w    = (const float*)d_in[4];
  const float* agg_b    = (const float*)d_in[5];
  const float* orig_w   = (const float*)d_in[6];
  const float* orig_b   = (const float*)d_in[7];
  float* out = (float*)d_out;

  // workspace (~44 MiB): Vp | vbf | c | xorig | sge | swt | xbf | Y
  char* ws = (char*)d_ws;
  const size_t MB = 1024 * 1024;
  float*  Vp    = (float*)ws;                           // 4 MiB (4 partials)
  ushort* vbf   = (ushort*)(ws + 4 * MB);               // 0.5 MiB
  float*  c_arr = (float*)(ws + 4 * MB + 512 * 1024);   // 512 B
  float*  xorig = (float*)(ws + 5 * MB);                // 128 KiB
  int2*   sge   = (int2*)(ws + 6 * MB);                 // 256 KiB
  float2* swt   = (float2*)(ws + 6 * MB + 512 * 1024);  // 256 KiB
  ushort* xbf   = (ushort*)(ws + 8 * MB);               // 32 MiB
  float*  Y     = (float*)(ws + 40 * MB);               // 4 MiB

  hipMemsetAsync(Y, 0, (size_t)T_TOK * NV * sizeof(float), stream);

  dim3 vg(NGE, 8, 4);
  compute_v_part<<<vg, 256, 0, stream>>>(expert_w, agg_w, Vp);
  gating_kernel<<<T_TOK / 8, 256, 0, stream>>>(x, gate_w, orig_w, xbf, xorig, sge, swt);
  reduce_v<<<NV * HDIM / 2048, 256, 0, stream>>>(Vp, vbf);
  compute_c<<<NGE, 256, 0, stream>>>(expert_b, agg_w, c_arr);

  dim3 yg(T_TOK / 128, 4);
  ygemm<<<yg, 256, 0, stream>>>(xbf, vbf, Y);

  combine_kernel<<<T_TOK / 64, 256, 0, stream>>>(Y, c_arr, sge, swt, xorig,
                                                 orig_b, agg_b, out);
}